// Round 3
// baseline (330.839 us; speedup 1.0000x reference)
//
#include <hip/hip_runtime.h>

// 2D DWT (db2, symmetric pad, pywt-compatible) — register-only, no LDS, no barriers.
// x: (16,3,1024,1024) f32 -> cA, cH: (16,3,513,513) f32, concatenated in d_out.
//
// Vertical pass (axis -2): per-column in registers, 2-row carry + prefetch.
// Horizontal pass (axis -1): neighbor halo via __shfl_up(.,1); wave-boundary
// lanes (lane 0) carry an extra 2-column halo loaded from global (L1-hit).
// Thread t computes output cols j=t and j=t+256; thread 255 also j=512.
// y[i] = sum_k f_rev[k] * xp[2i+k]; xp[p] -> x[refl(p)].

#define N 1024
#define NOUT 513
#define TI 8
#define STRIPS ((NOUT + TI - 1) / TI)   // 65

__device__ __forceinline__ int refl(int p) {
    int r = p - 2;
    r = (r < 0) ? (-1 - r) : r;
    r = (r > N - 1) ? (2 * N - 1 - r) : r;
    return r;
}

__device__ __forceinline__ float2 vfilt(float f0, float f1, float f2, float f3,
                                        float2 a, float2 b, float2 c, float2 d) {
    float2 r;
    r.x = f0 * a.x + f1 * b.x + f2 * c.x + f3 * d.x;
    r.y = f0 * a.y + f1 * b.y + f2 * c.y + f3 * d.y;
    return r;
}

__global__ __launch_bounds__(256, 4) void dwt2_reg(const float* __restrict__ x,
                                                   float* __restrict__ out) {
    // reversed filter taps (true convolution)
    const float l0 =  0.48296291314469025f;
    const float l1 =  0.836516303737469f;
    const float l2 =  0.22414386804185735f;
    const float l3 = -0.12940952255092145f;
    const float h0 = -0.12940952255092145f;
    const float h1 = -0.22414386804185735f;
    const float h2 =  0.836516303737469f;
    const float h3 = -0.48296291314469025f;

    const int strip = blockIdx.x;
    const int img   = blockIdx.y;
    const int i0 = strip * TI;
    const int t  = threadIdx.x;
    const int lane = t & 63;

    const float* __restrict__ xim = x + (size_t)img * N * N;
    const size_t plane = (size_t)NOUT * NOUT;
    float* __restrict__ cA = out + (size_t)img * plane;
    float* __restrict__ cH = out + ((size_t)48 + img) * plane;

    int nrows = NOUT - i0; if (nrows > TI) nrows = TI;

    const int c0 = 2 * t;          // half 0: input cols 2t, 2t+1   -> output j = t
    const int c1 = 2 * t + 512;    // half 1: input cols 2t+512,513 -> output j = t+256
    const bool isb = (lane == 0);           // wave-boundary lane
    const bool b0v = isb && (t != 0);       // half-0 halo valid (t=0 uses mirror)

#define LD2(row, col) (*reinterpret_cast<const float2*>(xim + (size_t)(row) * N + (col)))

    // prologue: xp rows 2*i0 .. 2*i0+3
    int p = 2 * i0;
    int ra = refl(p), rb = refl(p + 1), rc = refl(p + 2), rd = refl(p + 3);
    float2 a00 = LD2(ra, c0), a01 = LD2(rb, c0);
    float2 b00 = LD2(rc, c0), b01 = LD2(rd, c0);
    float2 a10 = LD2(ra, c1), a11 = LD2(rb, c1);
    float2 b10 = LD2(rc, c1), b11 = LD2(rd, c1);
    float2 am0, am1, bm0, bm1;   // half-0 boundary halo (cols c0-2,c0-1), lane0 & t>0
    float2 an0, an1, bn0, bn1;   // half-1 boundary halo (cols c1-2,c1-1), lane0
    am0 = am1 = bm0 = bm1 = make_float2(0.f, 0.f);
    an0 = an1 = bn0 = bn1 = make_float2(0.f, 0.f);
    if (b0v) { am0 = LD2(ra, c0 - 2); am1 = LD2(rb, c0 - 2);
               bm0 = LD2(rc, c0 - 2); bm1 = LD2(rd, c0 - 2); }
    if (isb) { an0 = LD2(ra, c1 - 2); an1 = LD2(rb, c1 - 2);
               bn0 = LD2(rc, c1 - 2); bn1 = LD2(rd, c1 - 2); }

    for (int ii = 0; ii < nrows; ++ii) {
        const int i = i0 + ii;

        // ---- vertical transform (registers) ----
        float2 Lo0 = vfilt(l0, l1, l2, l3, a00, a01, b00, b01);
        float2 Hi0 = vfilt(h0, h1, h2, h3, a00, a01, b00, b01);
        float2 Lo1 = vfilt(l0, l1, l2, l3, a10, a11, b10, b11);
        float2 Hi1 = vfilt(h0, h1, h2, h3, a10, a11, b10, b11);
        float2 LoB0 = vfilt(l0, l1, l2, l3, am0, am1, bm0, bm1);
        float2 HiB0 = vfilt(h0, h1, h2, h3, am0, am1, bm0, bm1);
        float2 LoB1 = vfilt(l0, l1, l2, l3, an0, an1, bn0, bn1);
        float2 HiB1 = vfilt(h0, h1, h2, h3, an0, an1, bn0, bn1);

        // ---- shift carry + prefetch next row pair (overlaps rest of iter) ----
        a00 = b00; a01 = b01; a10 = b10; a11 = b11;
        am0 = bm0; am1 = bm1; an0 = bn0; an1 = bn1;
        const int pn = 2 * i + 4;
        const int rn0 = refl(pn), rn1 = refl(pn + 1);
        b00 = LD2(rn0, c0); b01 = LD2(rn1, c0);
        b10 = LD2(rn0, c1); b11 = LD2(rn1, c1);
        if (b0v) { bm0 = LD2(rn0, c0 - 2); bm1 = LD2(rn1, c0 - 2); }
        if (isb) { bn0 = LD2(rn0, c1 - 2); bn1 = LD2(rn1, c1 - 2); }

        // ---- horizontal halo via intra-wave shuffle ----
        float Lm20 = __shfl_up(Lo0.x, 1);
        float Lm10 = __shfl_up(Lo0.y, 1);
        float Hm20 = __shfl_up(Hi0.x, 1);
        float Hm10 = __shfl_up(Hi0.y, 1);
        float Lm21 = __shfl_up(Lo1.x, 1);
        float Lm11 = __shfl_up(Lo1.y, 1);
        float Hm21 = __shfl_up(Hi1.x, 1);
        float Hm11 = __shfl_up(Hi1.y, 1);
        if (isb) {
            if (t == 0) {  // j=0: cols (1,0,0,1) mirror
                Lm20 = Lo0.y; Lm10 = Lo0.x; Hm20 = Hi0.y; Hm10 = Hi0.x;
            } else {
                Lm20 = LoB0.x; Lm10 = LoB0.y; Hm20 = HiB0.x; Hm10 = HiB0.y;
            }
            Lm21 = LoB1.x; Lm11 = LoB1.y; Hm21 = HiB1.x; Hm11 = HiB1.y;
        }

        // ---- horizontal transform + coalesced stores ----
        const float vA0 = l0 * Lm20 + l1 * Lm10 + l2 * Lo0.x + l3 * Lo0.y;
        const float vH0 = l0 * Hm20 + l1 * Hm10 + l2 * Hi0.x + l3 * Hi0.y;
        const float vA1 = l0 * Lm21 + l1 * Lm11 + l2 * Lo1.x + l3 * Lo1.y;
        const float vH1 = l0 * Hm21 + l1 * Hm11 + l2 * Hi1.x + l3 * Hi1.y;
        const size_t ro = (size_t)i * NOUT;
        cA[ro + t] = vA0;
        cH[ro + t] = vH0;
        cA[ro + t + 256] = vA1;
        cH[ro + t + 256] = vH1;
        if (t == 255) {  // j=512: cols (1022,1023,1023,1022)
            cA[ro + 512] = (l0 + l3) * Lo1.x + (l1 + l2) * Lo1.y;
            cH[ro + 512] = (l0 + l3) * Hi1.x + (l1 + l2) * Hi1.y;
        }
    }
#undef LD2
}

extern "C" void kernel_launch(void* const* d_in, const int* in_sizes, int n_in,
                              void* d_out, int out_size, void* d_ws, size_t ws_size,
                              hipStream_t stream) {
    (void)in_sizes; (void)n_in; (void)d_ws; (void)ws_size; (void)out_size;
    const float* x = (const float*)d_in[0];
    float* out = (float*)d_out;
    dim3 grid(STRIPS, 48);    // 65 x 48 = 3120 blocks, no LDS -> occupancy VGPR-bound
    dim3 block(256);
    dwt2_reg<<<grid, block, 0, stream>>>(x, out);
}